// Round 2
// baseline (695.688 us; speedup 1.0000x reference)
//
#include <hip/hip_runtime.h>

// ---------------------------------------------------------------------------
// 2-layer LSTM (Keras gates i,f,g,o) + Dense(27) + softmax. fp32.
// B=32768, T=21, F=126, U=8.
//
// Two-phase design (R2): the input projection x@W1k has no sequential
// dependence, so hoist it into a massively parallel GEMM (10752 waves,
// memory-bound ~75us), then run the recurrence on the 4x smaller Z tensor
// (88 MB vs 347 MB) with one wave per 64 samples, fully redundant per wave:
// no LDS, no barriers, register-double-buffered prefetch of z[t+1].
// R1 failure mode this fixes: fused kernel capped at 2 waves/SIMD ->
// latency-bound at 23% occupancy, 40% VALU, 8% HBM.
//
// Z layout: [grp][t][col(32)][sample-in-grp(64)] so that both the GEMM's
// stores and the recurrence's loads are lane-consecutive (256 B/inst).
// Weights are read at wave-uniform addresses -> scalar pipe (s_load),
// zero VMEM/LDS cost (verified R1: SGPR=112, 0 bank conflicts).
// ---------------------------------------------------------------------------

namespace {
constexpr int T_  = 21;
constexpr int FIN = 126;
constexpr int U_  = 8;
constexpr int NC  = 27;
constexpr int ZC  = 4 * U_;              // 32 gate columns
constexpr int ROW = T_ * FIN;            // 2646 floats per sample
constexpr size_t ZGRP = (size_t)T_ * ZC * 64;   // floats of Z per 64-sample group
}

__device__ __forceinline__ float sigm(float x) {
  return __builtin_amdgcn_rcpf(1.0f + __expf(-x));
}
__device__ __forceinline__ float tanh_f(float x) {
  return 1.0f - 2.0f * __builtin_amdgcn_rcpf(1.0f + __expf(2.0f * x));
}

// ---- Phase 1: Z[gl][t][c][sl] = b1[c] + sum_f x[b][t][f] * W1k[f][c] -------
// grid = (ceil(ngrp/4), 21), block = 256 (4 waves; wave w handles grp g0+bx*4+w)
__global__ __launch_bounds__(256) void zin_gemm(
    const float* __restrict__ X, const float* __restrict__ W1k,
    const float* __restrict__ b1, float* __restrict__ Z,
    int g0, int g1)
{
  const int sl  = threadIdx.x & 63;
  const int wv  = __builtin_amdgcn_readfirstlane(threadIdx.x >> 6);
  const int grp = g0 + blockIdx.x * 4 + wv;
  if (grp >= g1) return;
  const int t = blockIdx.y;
  const int b = grp * 64 + sl;

  float acc[ZC];
  #pragma unroll
  for (int c = 0; c < ZC; ++c) acc[c] = b1[c];

  // 504 B contiguous per lane; 8B-aligned (ROW*4 and FIN*4 are both 8B mult.)
  const float2* xr = reinterpret_cast<const float2*>(X + (size_t)b * ROW + t * FIN);
  #pragma unroll 3
  for (int q = 0; q < 63; ++q) {
    float2 xv = xr[q];
    #pragma unroll
    for (int c = 0; c < ZC; ++c) acc[c] = fmaf(xv.x, W1k[(2 * q) * ZC + c], acc[c]);
    #pragma unroll
    for (int c = 0; c < ZC; ++c) acc[c] = fmaf(xv.y, W1k[(2 * q + 1) * ZC + c], acc[c]);
  }

  float* zp = Z + (size_t)(grp - g0) * ZGRP + (size_t)t * ZC * 64 + sl;
  #pragma unroll
  for (int c = 0; c < ZC; ++c) zp[c * 64] = acc[c];   // 256 B contiguous / inst
}

// ---- Phase 2: recurrence. One wave per 64-sample group; no LDS/barriers. ---
// grid = (ngrp_chunk), block = 64.
__global__ __launch_bounds__(64) void lstm_rec(
    const float* __restrict__ Z,
    const float* __restrict__ W1r,
    const float* __restrict__ W2k, const float* __restrict__ W2r,
    const float* __restrict__ b2,
    const float* __restrict__ Wd, const float* __restrict__ bd,
    float* __restrict__ out, int g0, int g1)
{
  const int sl  = threadIdx.x & 63;
  const int grp = g0 + blockIdx.x;
  if (grp >= g1) return;

  const float* zb = Z + (size_t)(grp - g0) * ZGRP + sl;

  float h1[U_], c1[U_], h2[U_], c2[U_];
  #pragma unroll
  for (int u = 0; u < U_; ++u) { h1[u] = 0.f; c1[u] = 0.f; h2[u] = 0.f; c2[u] = 0.f; }

  float zc[ZC], zn[ZC];
  #pragma unroll
  for (int c = 0; c < ZC; ++c) zc[c] = zb[c * 64];    // t=0, coalesced

  for (int t = 0; t < T_; ++t) {
    // prefetch z[t+1] early; its latency overlaps the whole timestep body
    if (t + 1 < T_) {
      const float* zt = zb + (size_t)(t + 1) * ZC * 64;
      #pragma unroll
      for (int c = 0; c < ZC; ++c) zn[c] = zt[c * 64];
    }

    // layer 1: z1 = zc + h1 @ W1r (all 32 columns, redundant across nothing)
    float z1[ZC];
    #pragma unroll
    for (int c = 0; c < ZC; ++c) z1[c] = zc[c];
    #pragma unroll
    for (int k = 0; k < U_; ++k) {
      float hv = h1[k];
      #pragma unroll
      for (int c = 0; c < ZC; ++c) z1[c] = fmaf(hv, W1r[k * ZC + c], z1[c]);
    }
    #pragma unroll
    for (int u = 0; u < U_; ++u) {
      float iv = sigm(z1[u]), fv = sigm(z1[U_ + u]);
      float gv = tanh_f(z1[2 * U_ + u]), ov = sigm(z1[3 * U_ + u]);
      float cn = fv * c1[u] + iv * gv;
      c1[u] = cn;
      h1[u] = ov * tanh_f(cn);
    }

    // layer 2: z2 = b2 + h1 @ W2k + h2 @ W2r
    float z2[ZC];
    #pragma unroll
    for (int c = 0; c < ZC; ++c) z2[c] = b2[c];
    #pragma unroll
    for (int k = 0; k < U_; ++k) {
      float hv = h1[k];
      #pragma unroll
      for (int c = 0; c < ZC; ++c) z2[c] = fmaf(hv, W2k[k * ZC + c], z2[c]);
    }
    #pragma unroll
    for (int k = 0; k < U_; ++k) {
      float hv = h2[k];
      #pragma unroll
      for (int c = 0; c < ZC; ++c) z2[c] = fmaf(hv, W2r[k * ZC + c], z2[c]);
    }
    #pragma unroll
    for (int u = 0; u < U_; ++u) {
      float iv = sigm(z2[u]), fv = sigm(z2[U_ + u]);
      float gv = tanh_f(z2[2 * U_ + u]), ov = sigm(z2[3 * U_ + u]);
      float cn = fv * c2[u] + iv * gv;
      c2[u] = cn;
      h2[u] = ov * tanh_f(cn);
    }

    #pragma unroll
    for (int c = 0; c < ZC; ++c) zc[c] = zn[c];
  }

  // Dense(27) + softmax on final h2
  float lg[NC];
  float m = -1e30f;
  #pragma unroll
  for (int c = 0; c < NC; ++c) {
    float acc = bd[c];
    #pragma unroll
    for (int k = 0; k < U_; ++k) acc = fmaf(h2[k], Wd[k * NC + c], acc);
    lg[c] = acc;
    m = fmaxf(m, acc);
  }
  float ssum = 0.f;
  #pragma unroll
  for (int c = 0; c < NC; ++c) {
    float e = __expf(lg[c] - m);
    lg[c] = e;
    ssum += e;
  }
  float inv = 1.0f / ssum;
  float* op = out + (size_t)(grp * 64 + sl) * NC;
  #pragma unroll
  for (int c = 0; c < NC; ++c) op[c] = lg[c] * inv;
}

extern "C" void kernel_launch(void* const* d_in, const int* in_sizes, int n_in,
                              void* d_out, int out_size, void* d_ws, size_t ws_size,
                              hipStream_t stream) {
  const float* X   = (const float*)d_in[0];
  const float* W1k = (const float*)d_in[1];
  const float* W1r = (const float*)d_in[2];
  const float* b1  = (const float*)d_in[3];
  const float* W2k = (const float*)d_in[4];
  const float* W2r = (const float*)d_in[5];
  const float* b2  = (const float*)d_in[6];
  const float* Wd  = (const float*)d_in[7];
  const float* bd  = (const float*)d_in[8];
  float* out = (float*)d_out;
  float* Z   = (float*)d_ws;

  const int B    = in_sizes[0] / ROW;   // 32768
  const int ngrp = B / 64;              // 512

  // chunk the group range so Z fits in d_ws (1 chunk if ws >= ~88 MB)
  const size_t zgrp_bytes = ZGRP * sizeof(float);       // 172032 B
  int gpc = (int)((ws_size / zgrp_bytes));
  if (gpc < 1) gpc = 1;
  if (gpc > ngrp) gpc = ngrp;

  for (int g0 = 0; g0 < ngrp; g0 += gpc) {
    int g1 = g0 + gpc;
    if (g1 > ngrp) g1 = ngrp;
    int n = g1 - g0;
    dim3 ggrid((n + 3) / 4, T_);
    zin_gemm<<<ggrid, 256, 0, stream>>>(X, W1k, b1, Z, g0, g1);
    lstm_rec<<<dim3(n), 64, 0, stream>>>(Z, W1r, W2k, W2r, b2, Wd, bd, out, g0, g1);
  }
}

// Round 3
// 617.985 us; speedup vs baseline: 1.1257x; 1.1257x over previous
//
#include <hip/hip_runtime.h>

// ---------------------------------------------------------------------------
// 2-layer LSTM (Keras gates i,f,g,o) + Dense(27) + softmax. fp32.
// B=32768, T=21, F=126, U=8.
//
// Phase 1 (zin_gemm): Z = b1 + x @ W1k for all B*T rows.
//   R2 failure: per-lane row-major reads -> 64 lines per load inst, L1
//   thrash (wave WS = 32KB = L1), compiler strip-mined acc[32] (VGPR=24)
//   re-reading x -> FETCH 512MB, 2.45 TB/s, VALU 15%.
//   R3 fix: R1's proven LDS staging (coalesced 504B runs, 0 conflicts) +
//   per-wave float4-pair accumulators (8 cols/wave, no strip-mining),
//   block = 64 samples x 1 timestep, grid 512x21 -> ~5 blocks/CU.
//
// Phase 2 (lstm_rec): recurrence on Z (88MB), one wave per 64 samples,
//   no LDS/barriers, register-prefetch of z[t+1]. Weights via scalar pipe.
//
// Z layout: [grp][t][col(32)][sample(64)] -> GEMM stores and rec loads are
// both lane-consecutive (256 B/inst).
// ---------------------------------------------------------------------------

namespace {
constexpr int T_  = 21;
constexpr int FIN = 126;
constexpr int U_  = 8;
constexpr int NC  = 27;
constexpr int ZC  = 4 * U_;              // 32 gate columns
constexpr int ROW = T_ * FIN;            // 2646 floats per sample
constexpr size_t ZGRP = (size_t)T_ * ZC * 64;   // floats of Z per 64-sample group
}

__device__ __forceinline__ float sigm(float x) {
  return __builtin_amdgcn_rcpf(1.0f + __expf(-x));
}
__device__ __forceinline__ float tanh_f(float x) {
  return 1.0f - 2.0f * __builtin_amdgcn_rcpf(1.0f + __expf(2.0f * x));
}

// ---- Phase 1: Z[g][t][c][sl] = b1[c] + sum_f x[b][t][f] * W1k[f][c] --------
// grid = (ngrp_chunk, 21), block = 256.
__global__ __launch_bounds__(256) void zin_gemm(
    const float* __restrict__ X, const float* __restrict__ W1k,
    const float* __restrict__ b1, float* __restrict__ Z,
    int g0)
{
  __shared__ __align__(16) float xbuf[64 * FIN];   // 32256 B

  const int tid = threadIdx.x;
  const int sl  = tid & 63;
  const int wv  = __builtin_amdgcn_readfirstlane(tid >> 6);  // col group
  const int grp = g0 + blockIdx.x;
  const int t   = blockIdx.y;

  // ---- stage x[grp*64 .. +64, t, :] into LDS; 504 B contiguous runs ----
  const float* xbase = X + (size_t)grp * 64 * ROW + t * FIN;
  #pragma unroll
  for (int k = 0; k < 16; ++k) {
    int j = tid + k * 256;                 // over 64*63 float2 elements
    if (j < 64 * 63) {
      int s = j / 63;
      int q = j - s * 63;
      float2 v = *reinterpret_cast<const float2*>(xbase + (size_t)s * ROW + 2 * q);
      *reinterpret_cast<float2*>(&xbuf[s * FIN + 2 * q]) = v;
    }
  }
  __syncthreads();

  // ---- this wave's 8 columns: [8wv, 8wv+8) ----
  const float4* Wk4 = reinterpret_cast<const float4*>(W1k) + 2 * wv;
  float4 za = reinterpret_cast<const float4*>(b1)[2 * wv];
  float4 zb = reinterpret_cast<const float4*>(b1)[2 * wv + 1];

  const float2* xr = reinterpret_cast<const float2*>(&xbuf[sl * FIN]);
  #pragma unroll 3
  for (int q = 0; q < 63; ++q) {
    float2 xv = xr[q];
    float4 wa0 = Wk4[(2 * q) * 8];
    float4 wb0 = Wk4[(2 * q) * 8 + 1];
    float4 wa1 = Wk4[(2 * q + 1) * 8];
    float4 wb1 = Wk4[(2 * q + 1) * 8 + 1];
    za.x = fmaf(xv.x, wa0.x, za.x); za.y = fmaf(xv.x, wa0.y, za.y);
    za.z = fmaf(xv.x, wa0.z, za.z); za.w = fmaf(xv.x, wa0.w, za.w);
    zb.x = fmaf(xv.x, wb0.x, zb.x); zb.y = fmaf(xv.x, wb0.y, zb.y);
    zb.z = fmaf(xv.x, wb0.z, zb.z); zb.w = fmaf(xv.x, wb0.w, zb.w);
    za.x = fmaf(xv.y, wa1.x, za.x); za.y = fmaf(xv.y, wa1.y, za.y);
    za.z = fmaf(xv.y, wa1.z, za.z); za.w = fmaf(xv.y, wa1.w, za.w);
    zb.x = fmaf(xv.y, wb1.x, zb.x); zb.y = fmaf(xv.y, wb1.y, zb.y);
    zb.z = fmaf(xv.y, wb1.z, zb.z); zb.w = fmaf(xv.y, wb1.w, zb.w);
  }

  // ---- store: lane-consecutive, 256 B per inst ----
  float* zp = Z + (size_t)(grp - g0) * ZGRP + (size_t)t * ZC * 64
            + (size_t)(8 * wv) * 64 + sl;
  zp[0 * 64] = za.x; zp[1 * 64] = za.y; zp[2 * 64] = za.z; zp[3 * 64] = za.w;
  zp[4 * 64] = zb.x; zp[5 * 64] = zb.y; zp[6 * 64] = zb.z; zp[7 * 64] = zb.w;
}

// ---- Phase 2: recurrence. One wave per 64-sample group; no LDS/barriers. ---
__global__ __launch_bounds__(64) void lstm_rec(
    const float* __restrict__ Z,
    const float* __restrict__ W1r,
    const float* __restrict__ W2k, const float* __restrict__ W2r,
    const float* __restrict__ b2,
    const float* __restrict__ Wd, const float* __restrict__ bd,
    float* __restrict__ out, int g0)
{
  const int sl  = threadIdx.x & 63;
  const int grp = g0 + blockIdx.x;

  const float* zb = Z + (size_t)(grp - g0) * ZGRP + sl;

  float h1[U_], c1[U_], h2[U_], c2[U_];
  #pragma unroll
  for (int u = 0; u < U_; ++u) { h1[u] = 0.f; c1[u] = 0.f; h2[u] = 0.f; c2[u] = 0.f; }

  float zc[ZC], zn[ZC];
  #pragma unroll
  for (int c = 0; c < ZC; ++c) zc[c] = zb[c * 64];    // t=0, coalesced

  for (int t = 0; t < T_; ++t) {
    if (t + 1 < T_) {                    // prefetch z[t+1]; overlaps body
      const float* zt = zb + (size_t)(t + 1) * ZC * 64;
      #pragma unroll
      for (int c = 0; c < ZC; ++c) zn[c] = zt[c * 64];
    }

    // layer 1: z1 = zc + h1 @ W1r
    float z1[ZC];
    #pragma unroll
    for (int c = 0; c < ZC; ++c) z1[c] = zc[c];
    #pragma unroll
    for (int k = 0; k < U_; ++k) {
      float hv = h1[k];
      #pragma unroll
      for (int c = 0; c < ZC; ++c) z1[c] = fmaf(hv, W1r[k * ZC + c], z1[c]);
    }
    #pragma unroll
    for (int u = 0; u < U_; ++u) {
      float iv = sigm(z1[u]), fv = sigm(z1[U_ + u]);
      float gv = tanh_f(z1[2 * U_ + u]), ov = sigm(z1[3 * U_ + u]);
      float cn = fv * c1[u] + iv * gv;
      c1[u] = cn;
      h1[u] = ov * tanh_f(cn);
    }

    // layer 2: z2 = b2 + h1 @ W2k + h2 @ W2r
    float z2[ZC];
    #pragma unroll
    for (int c = 0; c < ZC; ++c) z2[c] = b2[c];
    #pragma unroll
    for (int k = 0; k < U_; ++k) {
      float hv = h1[k];
      #pragma unroll
      for (int c = 0; c < ZC; ++c) z2[c] = fmaf(hv, W2k[k * ZC + c], z2[c]);
    }
    #pragma unroll
    for (int k = 0; k < U_; ++k) {
      float hv = h2[k];
      #pragma unroll
      for (int c = 0; c < ZC; ++c) z2[c] = fmaf(hv, W2r[k * ZC + c], z2[c]);
    }
    #pragma unroll
    for (int u = 0; u < U_; ++u) {
      float iv = sigm(z2[u]), fv = sigm(z2[U_ + u]);
      float gv = tanh_f(z2[2 * U_ + u]), ov = sigm(z2[3 * U_ + u]);
      float cn = fv * c2[u] + iv * gv;
      c2[u] = cn;
      h2[u] = ov * tanh_f(cn);
    }

    #pragma unroll
    for (int c = 0; c < ZC; ++c) zc[c] = zn[c];
  }

  // Dense(27) + softmax on final h2
  float lg[NC];
  float m = -1e30f;
  #pragma unroll
  for (int c = 0; c < NC; ++c) {
    float acc = bd[c];
    #pragma unroll
    for (int k = 0; k < U_; ++k) acc = fmaf(h2[k], Wd[k * NC + c], acc);
    lg[c] = acc;
    m = fmaxf(m, acc);
  }
  float ssum = 0.f;
  #pragma unroll
  for (int c = 0; c < NC; ++c) {
    float e = __expf(lg[c] - m);
    lg[c] = e;
    ssum += e;
  }
  float inv = 1.0f / ssum;
  float* op = out + (size_t)(grp * 64 + sl) * NC;
  #pragma unroll
  for (int c = 0; c < NC; ++c) op[c] = lg[c] * inv;
}

extern "C" void kernel_launch(void* const* d_in, const int* in_sizes, int n_in,
                              void* d_out, int out_size, void* d_ws, size_t ws_size,
                              hipStream_t stream) {
  const float* X   = (const float*)d_in[0];
  const float* W1k = (const float*)d_in[1];
  const float* W1r = (const float*)d_in[2];
  const float* b1  = (const float*)d_in[3];
  const float* W2k = (const float*)d_in[4];
  const float* W2r = (const float*)d_in[5];
  const float* b2  = (const float*)d_in[6];
  const float* Wd  = (const float*)d_in[7];
  const float* bd  = (const float*)d_in[8];
  float* out = (float*)d_out;
  float* Z   = (float*)d_ws;

  const int B    = in_sizes[0] / ROW;   // 32768
  const int ngrp = B / 64;              // 512

  const size_t zgrp_bytes = ZGRP * sizeof(float);       // 172032 B
  int gpc = (int)(ws_size / zgrp_bytes);
  if (gpc < 1) gpc = 1;
  if (gpc > ngrp) gpc = ngrp;

  for (int g0 = 0; g0 < ngrp; g0 += gpc) {
    int g1 = g0 + gpc;
    if (g1 > ngrp) g1 = ngrp;
    int n = g1 - g0;
    zin_gemm<<<dim3(n, T_), 256, 0, stream>>>(X, W1k, b1, Z, g0);
    lstm_rec<<<dim3(n), 64, 0, stream>>>(Z, W1r, W2k, W2r, b2, Wd, bd, out, g0);
  }
}

// Round 4
// 583.556 us; speedup vs baseline: 1.1922x; 1.0590x over previous
//
#include <hip/hip_runtime.h>

// ---------------------------------------------------------------------------
// 2-layer LSTM (Keras gates i,f,g,o) + Dense(27) + softmax. fp32.
// B=32768, T=21, F=126, U=8.
//
// Phase 1 (zin_gemm): Z = b1 + x @ W1k, persistent per-group blocks.
//   R3 failure: 42 one-shot blocks/CU -> staging latency poorly overlapped,
//   W K$ re-read per block, boundary-line double fetch (~170us, 2.5TB/s).
//   R4: grid=512 groups, t-loop inside, double-buffered LDS (2x31.5KB,
//   1 barrier/t), VGPR prefetch of x(t+1) issued at top of t's compute.
//   W slice K$-hot across 21 t. Model: 2 blk/CU x 40.4KB/t x 21 ~ 69us.
//
// Phase 2 (lstm_rec): R1's proven gate-split recurrence, minus staging.
//   R2/R3 failure: 1 wave/SIMD (512 waves) -> all latency exposed (~120us).
//   R4: 512 blocks x 4 waves (wave = 8 gate cols, lane = sample) = 2048
//   waves = 2/SIMD on ALL SIMDs. z from global (coalesced, reg prefetch),
//   2 LDS exchanges + 2 barriers/t, state replicated per wave. ~15us.
//
// Z layout: [grp][t][col(32)][sample(64)] -> stores and loads both
// lane-consecutive (256 B/inst).
// ---------------------------------------------------------------------------

namespace {
constexpr int T_  = 21;
constexpr int FIN = 126;
constexpr int U_  = 8;
constexpr int NC  = 27;
constexpr int ZC  = 4 * U_;              // 32 gate columns
constexpr int ROW = T_ * FIN;            // 2646 floats per sample
constexpr size_t ZGRP = (size_t)T_ * ZC * 64;   // floats of Z per 64-sample group
}

__device__ __forceinline__ float sigm(float x) {
  return __builtin_amdgcn_rcpf(1.0f + __expf(-x));
}
__device__ __forceinline__ float tanh_f(float x) {
  return 1.0f - 2.0f * __builtin_amdgcn_rcpf(1.0f + __expf(2.0f * x));
}

// ---- Phase 1: Z[g][t][c][sl] = b1[c] + sum_f x[b][t][f] * W1k[f][c] --------
// grid = (ngrp_chunk), block = 256; persistent over t with LDS double-buffer.
__global__ __launch_bounds__(256) void zin_gemm(
    const float* __restrict__ X, const float* __restrict__ W1k,
    const float* __restrict__ b1, float* __restrict__ Z,
    int g0)
{
  __shared__ __align__(16) float xb[2][64 * FIN];   // 2 x 32256 B

  const int tid = threadIdx.x;
  const int sl  = tid & 63;
  const int wv  = __builtin_amdgcn_readfirstlane(tid >> 6);  // col group
  const int grp = g0 + blockIdx.x;

  // staging index decomposition (fixed per thread across t): j over 64*63
  // float2 elements; s = row (sample), q = float2 index within 504B slice.
  int  goff[16];   // global float-offset (sans t*FIN term)
  int  loff[16];   // LDS float-offset
  bool val[16];
  #pragma unroll
  for (int k = 0; k < 16; ++k) {
    int j = tid + k * 256;
    val[k] = (j < 64 * 63);
    int s = j / 63;
    int q = j - s * 63;
    goff[k] = s * ROW + 2 * q;
    loff[k] = s * FIN + 2 * q;
  }

  const float* xbase = X + (size_t)grp * 64 * ROW;

  // wave's 8 columns: [8wv, 8wv+8)
  const float4* Wk4 = reinterpret_cast<const float4*>(W1k) + 2 * wv;
  const float4  b1a = reinterpret_cast<const float4*>(b1)[2 * wv];
  const float4  b1b = reinterpret_cast<const float4*>(b1)[2 * wv + 1];

  // prologue: prefetch t=0 into registers
  float2 pf[16];
  #pragma unroll
  for (int k = 0; k < 16; ++k)
    if (val[k]) pf[k] = *reinterpret_cast<const float2*>(xbase + goff[k]);

  int p = 0;
  for (int t = 0; t < T_; ++t) {
    // drain prefetch into LDS buffer p
    #pragma unroll
    for (int k = 0; k < 16; ++k)
      if (val[k]) *reinterpret_cast<float2*>(&xb[p][loff[k]]) = pf[k];
    __syncthreads();

    // issue prefetch for t+1 (latency covered by t's compute below)
    if (t + 1 < T_) {
      const float* xt = xbase + (t + 1) * FIN;
      #pragma unroll
      for (int k = 0; k < 16; ++k)
        if (val[k]) pf[k] = *reinterpret_cast<const float2*>(xt + goff[k]);
    }

    // compute this wave's 8 columns for sample sl
    float4 za = b1a, zb = b1b;
    const float2* xr = reinterpret_cast<const float2*>(&xb[p][sl * FIN]);
    #pragma unroll 3
    for (int q = 0; q < 63; ++q) {
      float2 xv = xr[q];
      float4 wa0 = Wk4[(2 * q) * 8];
      float4 wb0 = Wk4[(2 * q) * 8 + 1];
      float4 wa1 = Wk4[(2 * q + 1) * 8];
      float4 wb1 = Wk4[(2 * q + 1) * 8 + 1];
      za.x = fmaf(xv.x, wa0.x, za.x); za.y = fmaf(xv.x, wa0.y, za.y);
      za.z = fmaf(xv.x, wa0.z, za.z); za.w = fmaf(xv.x, wa0.w, za.w);
      zb.x = fmaf(xv.x, wb0.x, zb.x); zb.y = fmaf(xv.x, wb0.y, zb.y);
      zb.z = fmaf(xv.x, wb0.z, zb.z); zb.w = fmaf(xv.x, wb0.w, zb.w);
      za.x = fmaf(xv.y, wa1.x, za.x); za.y = fmaf(xv.y, wa1.y, za.y);
      za.z = fmaf(xv.y, wa1.z, za.z); za.w = fmaf(xv.y, wa1.w, za.w);
      zb.x = fmaf(xv.y, wb1.x, zb.x); zb.y = fmaf(xv.y, wb1.y, zb.y);
      zb.z = fmaf(xv.y, wb1.z, zb.z); zb.w = fmaf(xv.y, wb1.w, zb.w);
    }

    // store: lane-consecutive, 256 B per inst
    float* zp = Z + (size_t)(grp - g0) * ZGRP + (size_t)t * ZC * 64
              + (size_t)(8 * wv) * 64 + sl;
    zp[0 * 64] = za.x; zp[1 * 64] = za.y; zp[2 * 64] = za.z; zp[3 * 64] = za.w;
    zp[4 * 64] = zb.x; zp[5 * 64] = zb.y; zp[6 * 64] = zb.z; zp[7 * 64] = zb.w;

    p ^= 1;
  }
}

// ---- Phase 2: gate-split recurrence (R1 scheme on precomputed Z). ----------
// grid = (ngrp_chunk), block = 256 (4 waves; wave = 8 gate cols, lane = sample)
__global__ __launch_bounds__(256) void lstm_rec(
    const float* __restrict__ Z,
    const float* __restrict__ W1r,
    const float* __restrict__ W2k, const float* __restrict__ W2r,
    const float* __restrict__ b2,
    const float* __restrict__ Wd, const float* __restrict__ bd,
    float* __restrict__ out, int g0)
{
  __shared__ __align__(16) float zb1[ZC * 64];   // 8 KB
  __shared__ __align__(16) float zb2[ZC * 64];   // 8 KB

  const int tid = threadIdx.x;
  const int sl  = tid & 63;
  const int wv  = __builtin_amdgcn_readfirstlane(tid >> 6);
  const int grp = g0 + blockIdx.x;

  const float* zbase = Z + (size_t)(grp - g0) * ZGRP + (size_t)(8 * wv) * 64 + sl;

  const float4 b2a = reinterpret_cast<const float4*>(b2)[2 * wv];
  const float4 b2b = reinterpret_cast<const float4*>(b2)[2 * wv + 1];

  float h1[U_], c1[U_], h2[U_], c2[U_];
  #pragma unroll
  for (int u = 0; u < U_; ++u) { h1[u] = 0.f; c1[u] = 0.f; h2[u] = 0.f; c2[u] = 0.f; }

  // register prefetch of this wave's z slice (8 cols) for t=0
  float zn[8], zc[8];
  #pragma unroll
  for (int c = 0; c < 8; ++c) zn[c] = zbase[c * 64];

  for (int t = 0; t < T_; ++t) {
    #pragma unroll
    for (int c = 0; c < 8; ++c) zc[c] = zn[c];
    if (t + 1 < T_) {
      const float* zt = zbase + (size_t)(t + 1) * ZC * 64;
      #pragma unroll
      for (int c = 0; c < 8; ++c) zn[c] = zt[c * 64];
    }

    // ---- layer 1: z1 slice = zc + h1 @ W1r (cols [8wv, 8wv+8)) ----
    float z1[8];
    #pragma unroll
    for (int c = 0; c < 8; ++c) z1[c] = zc[c];
    #pragma unroll
    for (int k = 0; k < U_; ++k) {
      float hv = h1[k];
      #pragma unroll
      for (int c = 0; c < 8; ++c)
        z1[c] = fmaf(hv, W1r[k * ZC + 8 * wv + c], z1[c]);
    }
    #pragma unroll
    for (int c = 0; c < 8; ++c) zb1[(8 * wv + c) * 64 + sl] = z1[c];
    __syncthreads();

    // ---- LSTM1 state update (replicated in every wave) ----
    #pragma unroll
    for (int u = 0; u < U_; ++u) {
      float zi = zb1[u * 64 + sl];
      float zf = zb1[(U_ + u) * 64 + sl];
      float zg = zb1[(2 * U_ + u) * 64 + sl];
      float zo = zb1[(3 * U_ + u) * 64 + sl];
      float iv = sigm(zi), fv = sigm(zf), gv = tanh_f(zg), ov = sigm(zo);
      float cn = fv * c1[u] + iv * gv;
      c1[u] = cn;
      h1[u] = ov * tanh_f(cn);
    }

    // ---- layer 2: z2 slice = b2 + h1 @ W2k + h2 @ W2r ----
    float4 za = b2a, zbv = b2b;
    #pragma unroll
    for (int k = 0; k < U_; ++k) {
      float hv = h1[k];
      const float* w = &W2k[k * ZC + 8 * wv];
      za.x  = fmaf(hv, w[0], za.x);  za.y  = fmaf(hv, w[1], za.y);
      za.z  = fmaf(hv, w[2], za.z);  za.w  = fmaf(hv, w[3], za.w);
      zbv.x = fmaf(hv, w[4], zbv.x); zbv.y = fmaf(hv, w[5], zbv.y);
      zbv.z = fmaf(hv, w[6], zbv.z); zbv.w = fmaf(hv, w[7], zbv.w);
    }
    #pragma unroll
    for (int k = 0; k < U_; ++k) {
      float hv = h2[k];
      const float* w = &W2r[k * ZC + 8 * wv];
      za.x  = fmaf(hv, w[0], za.x);  za.y  = fmaf(hv, w[1], za.y);
      za.z  = fmaf(hv, w[2], za.z);  za.w  = fmaf(hv, w[3], za.w);
      zbv.x = fmaf(hv, w[4], zbv.x); zbv.y = fmaf(hv, w[5], zbv.y);
      zbv.z = fmaf(hv, w[6], zbv.z); zbv.w = fmaf(hv, w[7], zbv.w);
    }
    {
      float* zp = &zb2[(8 * wv) * 64 + sl];
      zp[0 * 64] = za.x;  zp[1 * 64] = za.y;  zp[2 * 64] = za.z;  zp[3 * 64] = za.w;
      zp[4 * 64] = zbv.x; zp[5 * 64] = zbv.y; zp[6 * 64] = zbv.z; zp[7 * 64] = zbv.w;
    }
    __syncthreads();

    // ---- LSTM2 state update (replicated) ----
    #pragma unroll
    for (int u = 0; u < U_; ++u) {
      float zi = zb2[u * 64 + sl];
      float zf = zb2[(U_ + u) * 64 + sl];
      float zg = zb2[(2 * U_ + u) * 64 + sl];
      float zo = zb2[(3 * U_ + u) * 64 + sl];
      float iv = sigm(zi), fv = sigm(zf), gv = tanh_f(zg), ov = sigm(zo);
      float cn = fv * c2[u] + iv * gv;
      c2[u] = cn;
      h2[u] = ov * tanh_f(cn);
    }
  }

  // ---- Dense(27) + softmax (redundant per wave; wave 0 stages the write) ----
  float lg[NC];
  float m = -1e30f;
  #pragma unroll
  for (int c = 0; c < NC; ++c) {
    float acc = bd[c];
    #pragma unroll
    for (int k = 0; k < U_; ++k) acc = fmaf(h2[k], Wd[k * NC + c], acc);
    lg[c] = acc;
    m = fmaxf(m, acc);
  }
  float ssum = 0.f;
  #pragma unroll
  for (int c = 0; c < NC; ++c) {
    float e = __expf(lg[c] - m);
    lg[c] = e;
    ssum += e;
  }
  float inv = 1.0f / ssum;
  if (wv == 0) {
    #pragma unroll
    for (int c = 0; c < NC; ++c) zb1[sl * NC + c] = lg[c] * inv;
  }
  __syncthreads();
  {
    float* oblk = out + (size_t)grp * 64 * NC;
    #pragma unroll
    for (int k = 0; k < 7; ++k) {
      int j = tid + k * 256;
      if (j < 64 * NC) oblk[j] = zb1[j];   // coalesced store
    }
  }
}

extern "C" void kernel_launch(void* const* d_in, const int* in_sizes, int n_in,
                              void* d_out, int out_size, void* d_ws, size_t ws_size,
                              hipStream_t stream) {
  const float* X   = (const float*)d_in[0];
  const float* W1k = (const float*)d_in[1];
  const float* W1r = (const float*)d_in[2];
  const float* b1  = (const float*)d_in[3];
  const float* W2k = (const float*)d_in[4];
  const float* W2r = (const float*)d_in[5];
  const float* b2  = (const float*)d_in[6];
  const float* Wd  = (const float*)d_in[7];
  const float* bd  = (const float*)d_in[8];
  float* out = (float*)d_out;
  float* Z   = (float*)d_ws;

  const int B    = in_sizes[0] / ROW;   // 32768
  const int ngrp = B / 64;              // 512

  const size_t zgrp_bytes = ZGRP * sizeof(float);       // 172032 B
  int gpc = (int)(ws_size / zgrp_bytes);
  if (gpc < 1) gpc = 1;
  if (gpc > ngrp) gpc = ngrp;

  for (int g0 = 0; g0 < ngrp; g0 += gpc) {
    int g1 = g0 + gpc;
    if (g1 > ngrp) g1 = ngrp;
    int n = g1 - g0;
    zin_gemm<<<dim3(n), 256, 0, stream>>>(X, W1k, b1, Z, g0);
    lstm_rec<<<dim3(n), 256, 0, stream>>>(Z, W1r, W2k, W2r, b2, Wd, bd, out, g0);
  }
}